// Round 4
// baseline (435.656 us; speedup 1.0000x reference)
//
#include <hip/hip_runtime.h>
#include <cmath>
#include <cstdint>

#define NLEVELS 16
#define TABLE_SZ (1u << 19)
#define NXCD 8

typedef float f4v __attribute__((ext_vector_type(4)));
typedef uint32_t u32x4 __attribute__((ext_vector_type(4)));

struct Params {
    uint32_t res[NLEVELS];
    uint32_t size[NLEVELS];
    uint64_t magic[NLEVELS];
};

__device__ __forceinline__ float bf_lo(uint32_t v) { return __uint_as_float(v << 16); }
__device__ __forceinline__ float bf_hi(uint32_t v) { return __uint_as_float(v & 0xFFFF0000u); }

__device__ __forceinline__ uint32_t pick4(u32x4 f, uint32_t j) {
    uint32_t e01 = (j & 1) ? f[1] : f[0];
    uint32_t e23 = (j & 1) ? f[3] : f[2];
    return (j & 2) ? e23 : e01;
}

// One level for one point: 4 quad-gathers (x-corner pairs) + rare straddle.
__device__ __forceinline__ void enc_level(
    float x0, float x1, float x2,
    const uint32_t* __restrict__ tl, uint32_t size, uint64_t magic, float fres,
    float& s0, float& s1)
{
    float xr0 = x0 * fres, xr1 = x1 * fres, xr2 = x2 * fres;
    int ci0 = (int)xr0, ci1 = (int)xr1, ci2 = (int)xr2;
    float cf0 = xr0 - (float)ci0;
    float cf1 = xr1 - (float)ci1;
    float cf2 = xr2 - (float)ci2;

    uint32_t c0u = (uint32_t)ci0, c0v = c0u + 1u;
    uint32_t h1a = (uint32_t)ci1 * 2654435761u; uint32_t h1b = h1a + 2654435761u;
    uint32_t h2a = (uint32_t)ci2 * 805459861u;  uint32_t h2b = h2a + 805459861u;
    float w0a = 1.0f - cf0, w1a = 1.0f - cf1, w2a = 1.0f - cf2;

    s0 = 0.0f; s1 = 0.0f;
#pragma unroll
    for (int pq = 0; pq < 4; ++pq) {   // (y,z) combo; corners 2pq, 2pq+1
        uint32_t tyz = ((pq & 1) ? h1b : h1a) ^ ((pq & 2) ? h2b : h2a);
        float wyz = ((pq & 1) ? cf1 : w1a) * ((pq & 2) ? cf2 : w2a);
        uint32_t hU = tyz ^ c0u;
        uint32_t hV = tyz ^ c0v;
        uint32_t rU = hU - (uint32_t)__umul64hi((uint64_t)hU, magic) * size;
        uint32_t rV = hV - (uint32_t)__umul64hi((uint64_t)hV, magic) * size;
        uint32_t base = rU & ~3u;
        u32x4 f = *reinterpret_cast<const u32x4*>(tl + base);
        uint32_t eU = pick4(f, rU & 3u);
        uint32_t eV;
        if ((rV & ~3u) == base) {
            eV = pick4(f, rV & 3u);
        } else {
            eV = tl[rV];               // straddle fallback (masked, minority lanes)
        }
        float wU = w0a * wyz, wV = cf0 * wyz;
        s0 = fmaf(bf_lo(eU), wU, s0);
        s1 = fmaf(bf_hi(eU), wU, s1);
        s0 = fmaf(bf_lo(eV), wV, s0);
        s1 = fmaf(bf_hi(eV), wV, s1);
    }
}

// ---- Kernel 1: fp32 tables -> bf16x2 tables in ws, slot-affine (slot s owns
// levels 2s, 2s+1) so lines land in the XCD L2 that will gather them.
__global__ __launch_bounds__(256) void convert_kernel(
    const float* __restrict__ tab, uint32_t* __restrict__ btab, Params p)
{
    int slot = blockIdx.x & (NXCD - 1);
    uint32_t cb = blockIdx.x >> 3;
    int l0 = slot * 2, l1 = l0 + 1;
    uint32_t n0 = p.size[l0], n1 = p.size[l1];
    uint32_t total = n0 + n1;
    uint32_t stride = (gridDim.x >> 3) * 256;
    for (uint32_t i = cb * 256 + threadIdx.x; i < total; i += stride) {
        int l; uint32_t e;
        if (i < n0) { l = l0; e = i; } else { l = l1; e = i - n0; }
        unsigned long long u = __builtin_nontemporal_load(
            (const unsigned long long*)(tab + ((size_t)l * TABLE_SZ + e) * 2));
        uint32_t bx = (uint32_t)u, by = (uint32_t)(u >> 32);
        bx = (bx + 0x7fffu + ((bx >> 16) & 1u)) >> 16;   // RNE fp32->bf16
        by = (by + 0x7fffu + ((by >> 16) & 1u)) >> 16;
        btab[(size_t)l * TABLE_SZ + e] = bx | (by << 16);
    }
}

// ---- Kernel 2: gather + trilerp. Level-pure per XCD slot (blockIdx%8 -> levels
// 2s,2s+1), 2 points per thread for MLP, direct f4v NT store to out.
__global__ __launch_bounds__(256) void gather_kernel(
    const float* __restrict__ x, const uint32_t* __restrict__ btab,
    f4v* __restrict__ out4, Params p)
{
    int slot = blockIdx.x & (NXCD - 1);
    int chunk = blockIdx.x >> 3;
    int pt0 = chunk * 512 + (int)threadIdx.x;
    int pt1 = pt0 + 256;

    float a0 = __builtin_nontemporal_load(&x[(size_t)pt0 * 3 + 0]);
    float a1 = __builtin_nontemporal_load(&x[(size_t)pt0 * 3 + 1]);
    float a2 = __builtin_nontemporal_load(&x[(size_t)pt0 * 3 + 2]);
    float b0 = __builtin_nontemporal_load(&x[(size_t)pt1 * 3 + 0]);
    float b1 = __builtin_nontemporal_load(&x[(size_t)pt1 * 3 + 1]);
    float b2 = __builtin_nontemporal_load(&x[(size_t)pt1 * 3 + 2]);

    int l0 = slot * 2, l1 = l0 + 1;
    const uint32_t* __restrict__ t0 = btab + (size_t)l0 * TABLE_SZ;
    const uint32_t* __restrict__ t1 = btab + (size_t)l1 * TABLE_SZ;
    uint32_t sz0 = p.size[l0], sz1 = p.size[l1];
    uint64_t mg0 = p.magic[l0], mg1 = p.magic[l1];
    float fr0 = (float)p.res[l0], fr1 = (float)p.res[l1];

    float pa0, pa1, pa2, pa3;   // point 0: level l0 (x2), level l1 (x2)
    float pb0, pb1, pb2, pb3;   // point 1
    enc_level(a0, a1, a2, t0, sz0, mg0, fr0, pa0, pa1);
    enc_level(b0, b1, b2, t0, sz0, mg0, fr0, pb0, pb1);
    enc_level(a0, a1, a2, t1, sz1, mg1, fr1, pa2, pa3);
    enc_level(b0, b1, b2, t1, sz1, mg1, fr1, pb2, pb3);

    f4v oa = { pa0, pa1, pa2, pa3 };
    f4v ob = { pb0, pb1, pb2, pb3 };
    __builtin_nontemporal_store(oa, out4 + (size_t)pt0 * 8 + slot);
    __builtin_nontemporal_store(ob, out4 + (size_t)pt1 * 8 + slot);
}

// ---- Fallback: direct fp32 kernel (used only if ws too small / odd N).
__global__ __launch_bounds__(256) void hashgrid_fallback(
    const float* __restrict__ x, const float* __restrict__ tables,
    float* __restrict__ out, int n_points, Params lp)
{
    int gid = blockIdx.x * blockDim.x + threadIdx.x;
    int n = gid >> 4;
    int l = gid & 15;
    if (n >= n_points) return;
    float x0 = x[(size_t)n * 3 + 0];
    float x1 = x[(size_t)n * 3 + 1];
    float x2 = x[(size_t)n * 3 + 2];
    uint32_t size = lp.size[l];
    uint64_t magic = lp.magic[l];
    float fres = (float)lp.res[l];
    float xr0 = x0 * fres, xr1 = x1 * fres, xr2 = x2 * fres;
    int ci0 = (int)xr0, ci1 = (int)xr1, ci2 = (int)xr2;
    float cf0 = xr0 - (float)ci0, cf1 = xr1 - (float)ci1, cf2 = xr2 - (float)ci2;
    uint32_t h0a = (uint32_t)ci0;               uint32_t h0b = h0a + 1u;
    uint32_t h1a = (uint32_t)ci1 * 2654435761u; uint32_t h1b = h1a + 2654435761u;
    uint32_t h2a = (uint32_t)ci2 * 805459861u;  uint32_t h2b = h2a + 805459861u;
    float w0a = 1.0f - cf0, w1a = 1.0f - cf1, w2a = 1.0f - cf2;
    const float2* t = reinterpret_cast<const float2*>(tables) + (size_t)l * TABLE_SZ;
    float s0 = 0.0f, s1 = 0.0f;
#pragma unroll
    for (int k = 0; k < 8; ++k) {
        uint32_t h = ((k & 1) ? h0b : h0a) ^ ((k & 2) ? h1b : h1a) ^ ((k & 4) ? h2b : h2a);
        uint32_t q = (uint32_t)__umul64hi((uint64_t)h, magic);
        h -= q * size;
        float w = ((k & 1) ? cf0 : w0a) * ((k & 2) ? cf1 : w1a) * ((k & 4) ? cf2 : w2a);
        float2 f = t[h];
        s0 = fmaf(f.x, w, s0);
        s1 = fmaf(f.y, w, s1);
    }
    reinterpret_cast<float2*>(out)[(size_t)n * NLEVELS + l] = make_float2(s0, s1);
}

extern "C" void kernel_launch(void* const* d_in, const int* in_sizes, int n_in,
                              void* d_out, int out_size, void* d_ws, size_t ws_size,
                              hipStream_t stream) {
    const float* x      = (const float*)d_in[0];
    const float* tables = (const float*)d_in[1];
    float* out          = (float*)d_out;
    int n_points = in_sizes[0] / 3;

    // Exact replication of the reference's double-precision level math.
    Params p;
    double b = exp((log(512.0) - log(16.0)) / 15.0);
    for (int i = 0; i < NLEVELS; ++i) {
        double r = floor(16.0 * pow(b, (double)i));
        uint32_t res = (uint32_t)r;
        uint64_t cube = (uint64_t)res * res * res;
        uint32_t size = (cube < (uint64_t)TABLE_SZ) ? (uint32_t)cube : TABLE_SZ;
        p.res[i] = res;
        p.size[i] = size;
        p.magic[i] = ~0ULL / size + 1ULL;   // exact floor-div magic for n < 2^32
    }

    const size_t TAB_BYTES = (size_t)NLEVELS * TABLE_SZ * 4;   // 32 MB bf16 tables

    if (ws_size < TAB_BYTES || (n_points & 511) != 0) {
        int total = n_points * NLEVELS;
        hashgrid_fallback<<<(total + 255) / 256, 256, 0, stream>>>(x, tables, out, n_points, p);
        return;
    }

    uint32_t* btab = (uint32_t*)d_ws;

    convert_kernel<<<128 * NXCD, 256, 0, stream>>>(tables, btab, p);

    int chunks = n_points / 512;
    gather_kernel<<<chunks * NXCD, 256, 0, stream>>>(x, btab, (f4v*)out, p);
}

// Round 6
// 369.650 us; speedup vs baseline: 1.1786x; 1.1786x over previous
//
#include <hip/hip_runtime.h>
#include <cmath>
#include <cstdint>

#define NLEVELS 16
#define TABLE_SZ (1u << 19)
#define MASK19 (TABLE_SZ - 1u)
#define NXCD 8

typedef float f4v __attribute__((ext_vector_type(4)));
typedef uint32_t u32x4 __attribute__((ext_vector_type(4)));

struct Params {
    uint32_t res[NLEVELS];
    uint32_t size[NLEVELS];
    uint64_t magic[NLEVELS];
};

__device__ __forceinline__ float bf_lo(uint32_t v) { return __uint_as_float(v << 16); }
__device__ __forceinline__ float bf_hi(uint32_t v) { return __uint_as_float(v & 0xFFFF0000u); }

__device__ __forceinline__ uint32_t pick4(u32x4 f, uint32_t j) {
    uint32_t e01 = (j & 1) ? f[1] : f[0];
    uint32_t e23 = (j & 1) ? f[3] : f[2];
    return (j & 2) ? e23 : e01;
}

__device__ __forceinline__ uint32_t rne_bf16(uint32_t u) {
    return (u + 0x7fffu + ((u >> 16) & 1u)) >> 16;
}
__device__ __forceinline__ uint32_t pack_bf(float a, float b) {
    return rne_bf16(__float_as_uint(a)) | (rne_bf16(__float_as_uint(b)) << 16);
}

// Uncapped level (size < 2^19): magic-mod residues, quad-paired x-corners.
__device__ __forceinline__ void enc_magic(
    float x0, float x1, float x2,
    const uint32_t* __restrict__ tl, uint32_t size, uint64_t magic, float fres,
    float& s0, float& s1)
{
    float xr0 = x0 * fres, xr1 = x1 * fres, xr2 = x2 * fres;
    int ci0 = (int)xr0, ci1 = (int)xr1, ci2 = (int)xr2;
    float cf0 = xr0 - (float)ci0;
    float cf1 = xr1 - (float)ci1;
    float cf2 = xr2 - (float)ci2;

    uint32_t c0u = (uint32_t)ci0, c0v = c0u + 1u;
    uint32_t h1a = (uint32_t)ci1 * 2654435761u; uint32_t h1b = h1a + 2654435761u;
    uint32_t h2a = (uint32_t)ci2 * 805459861u;  uint32_t h2b = h2a + 805459861u;
    float w0a = 1.0f - cf0, w1a = 1.0f - cf1, w2a = 1.0f - cf2;

    s0 = 0.0f; s1 = 0.0f;
#pragma unroll
    for (int pq = 0; pq < 4; ++pq) {
        uint32_t tyz = ((pq & 1) ? h1b : h1a) ^ ((pq & 2) ? h2b : h2a);
        float wyz = ((pq & 1) ? cf1 : w1a) * ((pq & 2) ? cf2 : w2a);
        uint32_t hU = tyz ^ c0u;
        uint32_t hV = tyz ^ c0v;
        uint32_t rU = hU - (uint32_t)__umul64hi((uint64_t)hU, magic) * size;
        uint32_t rV = hV - (uint32_t)__umul64hi((uint64_t)hV, magic) * size;
        uint32_t base = rU & ~3u;
        u32x4 f = *reinterpret_cast<const u32x4*>(tl + base);
        uint32_t eU = pick4(f, rU & 3u);
        uint32_t eV;
        if ((rV & ~3u) == base) {
            eV = pick4(f, rV & 3u);
        } else {
            eV = tl[rV];
        }
        float wU = w0a * wyz, wV = cf0 * wyz;
        s0 = fmaf(bf_lo(eU), wU, s0);
        s1 = fmaf(bf_hi(eU), wU, s1);
        s0 = fmaf(bf_lo(eV), wV, s0);
        s1 = fmaf(bf_hi(eV), wV, s1);
    }
}

// Capped level (size == 2^19): mod = AND, rV = rU ^ m, loop-invariant straddle.
__device__ __forceinline__ void enc_capped(
    float x0, float x1, float x2,
    const uint32_t* __restrict__ tl, float fres,
    float& s0, float& s1)
{
    float xr0 = x0 * fres, xr1 = x1 * fres, xr2 = x2 * fres;
    int ci0 = (int)xr0, ci1 = (int)xr1, ci2 = (int)xr2;
    float cf0 = xr0 - (float)ci0;
    float cf1 = xr1 - (float)ci1;
    float cf2 = xr2 - (float)ci2;

    uint32_t c0u = (uint32_t)ci0;
    uint32_t m = c0u ^ (c0u + 1u);          // low-ones mask
    uint32_t h1a = (uint32_t)ci1 * 2654435761u; uint32_t h1b = h1a + 2654435761u;
    uint32_t h2a = (uint32_t)ci2 * 805459861u;  uint32_t h2b = h2a + 805459861u;
    float w0a = 1.0f - cf0, w1a = 1.0f - cf1, w2a = 1.0f - cf2;
    bool nostrad = (m <= 3u);

    s0 = 0.0f; s1 = 0.0f;
#pragma unroll
    for (int pq = 0; pq < 4; ++pq) {
        uint32_t tyz = ((pq & 1) ? h1b : h1a) ^ ((pq & 2) ? h2b : h2a);
        float wyz = ((pq & 1) ? cf1 : w1a) * ((pq & 2) ? cf2 : w2a);
        uint32_t rU = (tyz ^ c0u) & MASK19;
        uint32_t rV = rU ^ m;
        uint32_t base = rU & ~3u;
        u32x4 f = *reinterpret_cast<const u32x4*>(tl + base);
        uint32_t eU = pick4(f, rU & 3u);
        uint32_t eV;
        if (nostrad) {
            eV = pick4(f, rV & 3u);
        } else {
            eV = tl[rV];
        }
        float wU = w0a * wyz, wV = cf0 * wyz;
        s0 = fmaf(bf_lo(eU), wU, s0);
        s1 = fmaf(bf_hi(eU), wU, s1);
        s0 = fmaf(bf_lo(eV), wV, s0);
        s1 = fmaf(bf_hi(eV), wV, s1);
    }
}

// ---- Kernel 1: fp32 tables -> bf16x2 tables; slot s owns levels s and s+8.
__global__ __launch_bounds__(256) void convert_kernel(
    const float* __restrict__ tab, uint32_t* __restrict__ btab, Params p)
{
    int slot = blockIdx.x & (NXCD - 1);
    uint32_t cb = blockIdx.x >> 3;
    int l0 = slot, l1 = slot + 8;
    uint32_t n0 = p.size[l0], n1 = p.size[l1];
    uint32_t total = n0 + n1;
    uint32_t stride = (gridDim.x >> 3) * 256;
    for (uint32_t i = cb * 256 + threadIdx.x; i < total; i += stride) {
        int l; uint32_t e;
        if (i < n0) { l = l0; e = i; } else { l = l1; e = i - n0; }
        unsigned long long u = __builtin_nontemporal_load(
            (const unsigned long long*)(tab + ((size_t)l * TABLE_SZ + e) * 2));
        btab[(size_t)l * TABLE_SZ + e] =
            rne_bf16((uint32_t)u) | (rne_bf16((uint32_t)(u >> 32)) << 16);
    }
}

// ---- Kernel 2: gather + trilerp. Slot s (blockIdx%8) does levels s (magic)
// and s+8 (capped). Packs both results as bf16x2 pair -> one 8B NT store.
__global__ __launch_bounds__(256) void gather_kernel(
    const float* __restrict__ x, const uint32_t* __restrict__ btab,
    unsigned long long* __restrict__ ws2, int p_lo, int passN, Params p)
{
    int slot = blockIdx.x & (NXCD - 1);
    int chunk = blockIdx.x >> 3;
    int rel = chunk * 256 + (int)threadIdx.x;
    int pt = p_lo + rel;

    float x0 = __builtin_nontemporal_load(&x[(size_t)pt * 3 + 0]);
    float x1 = __builtin_nontemporal_load(&x[(size_t)pt * 3 + 1]);
    float x2 = __builtin_nontemporal_load(&x[(size_t)pt * 3 + 2]);

    int l0 = slot, l1 = slot + 8;
    const uint32_t* __restrict__ t0 = btab + (size_t)l0 * TABLE_SZ;
    const uint32_t* __restrict__ t1 = btab + (size_t)l1 * TABLE_SZ;

    float a0, a1, b0, b1;
    enc_magic (x0, x1, x2, t0, p.size[l0], p.magic[l0], (float)p.res[l0], a0, a1);
    enc_capped(x0, x1, x2, t1, (float)p.res[l1], b0, b1);

    unsigned long long o = (unsigned long long)pack_bf(a0, a1)
                         | ((unsigned long long)pack_bf(b0, b1) << 32);
    __builtin_nontemporal_store(o, ws2 + (size_t)slot * passN + rel);
}

// ---- Kernel 3: unpack + transpose ws2[slot][pt] -> out[point][32] fp32.
__global__ __launch_bounds__(256) void transpose_kernel(
    const unsigned long long* __restrict__ ws2, f4v* __restrict__ out4,
    int p_lo, int passN)
{
    __shared__ uint32_t lds[256 * 17];
    int base = blockIdx.x * 256;
    int tid = threadIdx.x;
#pragma unroll
    for (int s = 0; s < NXCD; ++s) {
        unsigned long long v = __builtin_nontemporal_load(
            &ws2[(size_t)s * passN + base + tid]);
        lds[tid * 17 + s]     = (uint32_t)v;          // level s
        lds[tid * 17 + s + 8] = (uint32_t)(v >> 32);  // level s+8
    }
    __syncthreads();
    size_t ob = ((size_t)(p_lo + base)) * 8;
#pragma unroll
    for (int k = 0; k < 8; ++k) {
        int flat = k * 256 + tid;
        int ptl = flat >> 3, j = flat & 7;
        uint32_t u0 = lds[ptl * 17 + 2 * j];
        uint32_t u1 = lds[ptl * 17 + 2 * j + 1];
        f4v o = { bf_lo(u0), bf_hi(u0), bf_lo(u1), bf_hi(u1) };
        __builtin_nontemporal_store(o, out4 + ob + flat);
    }
}

// ---- Fallback: direct fp32 kernel (correct for any config).
__global__ __launch_bounds__(256) void hashgrid_fallback(
    const float* __restrict__ x, const float* __restrict__ tables,
    float* __restrict__ out, int n_points, Params lp)
{
    int gid = blockIdx.x * blockDim.x + threadIdx.x;
    int n = gid >> 4;
    int l = gid & 15;
    if (n >= n_points) return;
    float x0 = x[(size_t)n * 3 + 0];
    float x1 = x[(size_t)n * 3 + 1];
    float x2 = x[(size_t)n * 3 + 2];
    uint32_t size = lp.size[l];
    uint64_t magic = lp.magic[l];
    float fres = (float)lp.res[l];
    float xr0 = x0 * fres, xr1 = x1 * fres, xr2 = x2 * fres;
    int ci0 = (int)xr0, ci1 = (int)xr1, ci2 = (int)xr2;
    float cf0 = xr0 - (float)ci0, cf1 = xr1 - (float)ci1, cf2 = xr2 - (float)ci2;
    uint32_t h0a = (uint32_t)ci0;               uint32_t h0b = h0a + 1u;
    uint32_t h1a = (uint32_t)ci1 * 2654435761u; uint32_t h1b = h1a + 2654435761u;
    uint32_t h2a = (uint32_t)ci2 * 805459861u;  uint32_t h2b = h2a + 805459861u;
    float w0a = 1.0f - cf0, w1a = 1.0f - cf1, w2a = 1.0f - cf2;
    const float2* t = reinterpret_cast<const float2*>(tables) + (size_t)l * TABLE_SZ;
    float s0 = 0.0f, s1 = 0.0f;
#pragma unroll
    for (int k = 0; k < 8; ++k) {
        uint32_t h = ((k & 1) ? h0b : h0a) ^ ((k & 2) ? h1b : h1a) ^ ((k & 4) ? h2b : h2a);
        uint32_t q = (uint32_t)__umul64hi((uint64_t)h, magic);
        h -= q * size;
        float w = ((k & 1) ? cf0 : w0a) * ((k & 2) ? cf1 : w1a) * ((k & 4) ? cf2 : w2a);
        float2 f = t[h];
        s0 = fmaf(f.x, w, s0);
        s1 = fmaf(f.y, w, s1);
    }
    reinterpret_cast<float2*>(out)[(size_t)n * NLEVELS + l] = make_float2(s0, s1);
}

extern "C" void kernel_launch(void* const* d_in, const int* in_sizes, int n_in,
                              void* d_out, int out_size, void* d_ws, size_t ws_size,
                              hipStream_t stream) {
    const float* x      = (const float*)d_in[0];
    const float* tables = (const float*)d_in[1];
    float* out          = (float*)d_out;
    int n_points = in_sizes[0] / 3;

    // Exact replication of the reference's double-precision level math.
    Params p;
    double b = exp((log(512.0) - log(16.0)) / 15.0);
    for (int i = 0; i < NLEVELS; ++i) {
        double r = floor(16.0 * pow(b, (double)i));
        uint32_t res = (uint32_t)r;
        uint64_t cube = (uint64_t)res * res * res;
        uint32_t size = (cube < (uint64_t)TABLE_SZ) ? (uint32_t)cube : TABLE_SZ;
        p.res[i] = res;
        p.size[i] = size;
        p.magic[i] = ~0ULL / size + 1ULL;
    }
    // Structure assumption for the fast path: levels 0-7 uncapped, 8-15 capped.
    bool shape_ok = true;
    for (int s = 0; s < 8; ++s)
        shape_ok = shape_ok && (p.size[s] < TABLE_SZ) && (p.size[s + 8] == TABLE_SZ);

    const size_t TAB_BYTES = (size_t)NLEVELS * TABLE_SZ * 4;   // 32 MB bf16 tables
    size_t rem = (ws_size > TAB_BYTES) ? ws_size - TAB_BYTES : 0;
    int passN = (int)((rem / (NXCD * sizeof(unsigned long long))) & ~(size_t)255);
    if (passN > n_points) passN = n_points;

    if (!shape_ok || passN < 256 || (n_points & 255) != 0) {
        int total = n_points * NLEVELS;
        hashgrid_fallback<<<(total + 255) / 256, 256, 0, stream>>>(x, tables, out, n_points, p);
        return;
    }

    uint32_t* btab = (uint32_t*)d_ws;
    unsigned long long* ws2 = (unsigned long long*)((char*)d_ws + TAB_BYTES);

    convert_kernel<<<128 * NXCD, 256, 0, stream>>>(tables, btab, p);

    for (int p_lo = 0; p_lo < n_points; p_lo += passN) {
        int cnt = n_points - p_lo;
        if (cnt > passN) cnt = passN;
        int chunks = cnt / 256;
        gather_kernel<<<chunks * NXCD, 256, 0, stream>>>(x, btab, ws2, p_lo, cnt, p);
        transpose_kernel<<<chunks, 256, 0, stream>>>(ws2, (f4v*)out, p_lo, cnt);
    }
}

// Round 7
// 366.128 us; speedup vs baseline: 1.1899x; 1.0096x over previous
//
#include <hip/hip_runtime.h>
#include <cmath>
#include <cstdint>

#define NLEVELS 16
#define TABLE_SZ (1u << 19)
#define MASK19 (TABLE_SZ - 1u)
#define NXCD 8

typedef float f4v __attribute__((ext_vector_type(4)));
typedef uint32_t u32x4 __attribute__((ext_vector_type(4)));
typedef u32x4 u32x4u __attribute__((aligned(4)));   // 4B-aligned 16B window

struct Params {
    uint32_t res[NLEVELS];
    uint32_t size[NLEVELS];
    uint64_t magic[NLEVELS];
};

__device__ __forceinline__ float bf_lo(uint32_t v) { return __uint_as_float(v << 16); }
__device__ __forceinline__ float bf_hi(uint32_t v) { return __uint_as_float(v & 0xFFFF0000u); }

__device__ __forceinline__ uint32_t pick4(u32x4 f, uint32_t j) {
    uint32_t e01 = (j & 1) ? f[1] : f[0];
    uint32_t e23 = (j & 1) ? f[3] : f[2];
    return (j & 2) ? e23 : e01;
}

__device__ __forceinline__ uint32_t rne_bf16(uint32_t u) {
    return (u + 0x7fffu + ((u >> 16) & 1u)) >> 16;
}
__device__ __forceinline__ uint32_t pack_bf(float a, float b) {
    return rne_bf16(__float_as_uint(a)) | (rne_bf16(__float_as_uint(b)) << 16);
}

// Fetch the pair (tl[rU], tl[rV]) with one unaligned 16B window at min(rU,rV)
// when |rV-rU| <= 3 (P~0.83); else two scalar gathers.
__device__ __forceinline__ void pair_fetch(
    const uint32_t* __restrict__ tl, uint32_t rU, uint32_t rV,
    uint32_t& eU, uint32_t& eV)
{
    int32_t d = (int32_t)rV - (int32_t)rU;
    uint32_t ad = (uint32_t)(d >= 0 ? d : -d);
    uint32_t lo = d >= 0 ? rU : rV;
    if (ad <= 3u) {
        u32x4 f = *reinterpret_cast<const u32x4u*>(tl + lo);
        eU = pick4(f, rU - lo);
        eV = pick4(f, rV - lo);
    } else {
        eU = tl[rU];
        eV = tl[rV];
    }
}

// Uncapped level (size < 2^19): magic-mod residues, min-window paired fetch.
__device__ __forceinline__ void enc_magic(
    float x0, float x1, float x2,
    const uint32_t* __restrict__ tl, uint32_t size, uint64_t magic, float fres,
    float& s0, float& s1)
{
    float xr0 = x0 * fres, xr1 = x1 * fres, xr2 = x2 * fres;
    int ci0 = (int)xr0, ci1 = (int)xr1, ci2 = (int)xr2;
    float cf0 = xr0 - (float)ci0;
    float cf1 = xr1 - (float)ci1;
    float cf2 = xr2 - (float)ci2;

    uint32_t c0u = (uint32_t)ci0, c0v = c0u + 1u;
    uint32_t h1a = (uint32_t)ci1 * 2654435761u; uint32_t h1b = h1a + 2654435761u;
    uint32_t h2a = (uint32_t)ci2 * 805459861u;  uint32_t h2b = h2a + 805459861u;
    float w0a = 1.0f - cf0, w1a = 1.0f - cf1, w2a = 1.0f - cf2;

    s0 = 0.0f; s1 = 0.0f;
#pragma unroll
    for (int pq = 0; pq < 4; ++pq) {
        uint32_t tyz = ((pq & 1) ? h1b : h1a) ^ ((pq & 2) ? h2b : h2a);
        float wyz = ((pq & 1) ? cf1 : w1a) * ((pq & 2) ? cf2 : w2a);
        uint32_t hU = tyz ^ c0u;
        uint32_t hV = tyz ^ c0v;
        uint32_t rU = hU - (uint32_t)__umul64hi((uint64_t)hU, magic) * size;
        uint32_t rV = hV - (uint32_t)__umul64hi((uint64_t)hV, magic) * size;
        uint32_t eU, eV;
        pair_fetch(tl, rU, rV, eU, eV);
        float wU = w0a * wyz, wV = cf0 * wyz;
        s0 = fmaf(bf_lo(eU), wU, s0);
        s1 = fmaf(bf_hi(eU), wU, s1);
        s0 = fmaf(bf_lo(eV), wV, s0);
        s1 = fmaf(bf_hi(eV), wV, s1);
    }
}

// Capped level (size == 2^19): mod = AND, rV = rU ^ m, min-window paired fetch.
__device__ __forceinline__ void enc_capped(
    float x0, float x1, float x2,
    const uint32_t* __restrict__ tl, float fres,
    float& s0, float& s1)
{
    float xr0 = x0 * fres, xr1 = x1 * fres, xr2 = x2 * fres;
    int ci0 = (int)xr0, ci1 = (int)xr1, ci2 = (int)xr2;
    float cf0 = xr0 - (float)ci0;
    float cf1 = xr1 - (float)ci1;
    float cf2 = xr2 - (float)ci2;

    uint32_t c0u = (uint32_t)ci0;
    uint32_t m = c0u ^ (c0u + 1u);          // low-ones mask
    uint32_t h1a = (uint32_t)ci1 * 2654435761u; uint32_t h1b = h1a + 2654435761u;
    uint32_t h2a = (uint32_t)ci2 * 805459861u;  uint32_t h2b = h2a + 805459861u;
    float w0a = 1.0f - cf0, w1a = 1.0f - cf1, w2a = 1.0f - cf2;

    s0 = 0.0f; s1 = 0.0f;
#pragma unroll
    for (int pq = 0; pq < 4; ++pq) {
        uint32_t tyz = ((pq & 1) ? h1b : h1a) ^ ((pq & 2) ? h2b : h2a);
        float wyz = ((pq & 1) ? cf1 : w1a) * ((pq & 2) ? cf2 : w2a);
        uint32_t rU = (tyz ^ c0u) & MASK19;
        uint32_t rV = rU ^ m;
        uint32_t eU, eV;
        pair_fetch(tl, rU, rV, eU, eV);
        float wU = w0a * wyz, wV = cf0 * wyz;
        s0 = fmaf(bf_lo(eU), wU, s0);
        s1 = fmaf(bf_hi(eU), wU, s1);
        s0 = fmaf(bf_lo(eV), wV, s0);
        s1 = fmaf(bf_hi(eV), wV, s1);
    }
}

// ---- Kernel 1: fp32 tables -> bf16x2 tables; slot s owns levels s and s+8.
__global__ __launch_bounds__(256) void convert_kernel(
    const float* __restrict__ tab, uint32_t* __restrict__ btab, Params p)
{
    int slot = blockIdx.x & (NXCD - 1);
    uint32_t cb = blockIdx.x >> 3;
    int l0 = slot, l1 = slot + 8;
    uint32_t n0 = p.size[l0], n1 = p.size[l1];
    uint32_t total = n0 + n1;
    uint32_t stride = (gridDim.x >> 3) * 256;
    for (uint32_t i = cb * 256 + threadIdx.x; i < total; i += stride) {
        int l; uint32_t e;
        if (i < n0) { l = l0; e = i; } else { l = l1; e = i - n0; }
        unsigned long long u = __builtin_nontemporal_load(
            (const unsigned long long*)(tab + ((size_t)l * TABLE_SZ + e) * 2));
        btab[(size_t)l * TABLE_SZ + e] =
            rne_bf16((uint32_t)u) | (rne_bf16((uint32_t)(u >> 32)) << 16);
    }
}

// ---- Kernel 2: gather + trilerp. Slot s (blockIdx%8) does levels s (magic)
// and s+8 (capped). Packs both results as bf16x2 pair -> one 8B NT store.
__global__ __launch_bounds__(256) void gather_kernel(
    const float* __restrict__ x, const uint32_t* __restrict__ btab,
    unsigned long long* __restrict__ ws2, int p_lo, int passN, Params p)
{
    int slot = blockIdx.x & (NXCD - 1);
    int chunk = blockIdx.x >> 3;
    int rel = chunk * 256 + (int)threadIdx.x;
    int pt = p_lo + rel;

    float x0 = __builtin_nontemporal_load(&x[(size_t)pt * 3 + 0]);
    float x1 = __builtin_nontemporal_load(&x[(size_t)pt * 3 + 1]);
    float x2 = __builtin_nontemporal_load(&x[(size_t)pt * 3 + 2]);

    int l0 = slot, l1 = slot + 8;
    const uint32_t* __restrict__ t0 = btab + (size_t)l0 * TABLE_SZ;
    const uint32_t* __restrict__ t1 = btab + (size_t)l1 * TABLE_SZ;

    float a0, a1, b0, b1;
    enc_magic (x0, x1, x2, t0, p.size[l0], p.magic[l0], (float)p.res[l0], a0, a1);
    enc_capped(x0, x1, x2, t1, (float)p.res[l1], b0, b1);

    unsigned long long o = (unsigned long long)pack_bf(a0, a1)
                         | ((unsigned long long)pack_bf(b0, b1) << 32);
    __builtin_nontemporal_store(o, ws2 + (size_t)slot * passN + rel);
}

// ---- Kernel 3: unpack + transpose ws2[slot][pt] -> out[point][32] fp32.
__global__ __launch_bounds__(256) void transpose_kernel(
    const unsigned long long* __restrict__ ws2, f4v* __restrict__ out4,
    int p_lo, int passN)
{
    __shared__ uint32_t lds[256 * 17];
    int base = blockIdx.x * 256;
    int tid = threadIdx.x;
#pragma unroll
    for (int s = 0; s < NXCD; ++s) {
        unsigned long long v = __builtin_nontemporal_load(
            &ws2[(size_t)s * passN + base + tid]);
        lds[tid * 17 + s]     = (uint32_t)v;          // level s
        lds[tid * 17 + s + 8] = (uint32_t)(v >> 32);  // level s+8
    }
    __syncthreads();
    size_t ob = ((size_t)(p_lo + base)) * 8;
#pragma unroll
    for (int k = 0; k < 8; ++k) {
        int flat = k * 256 + tid;
        int ptl = flat >> 3, j = flat & 7;
        uint32_t u0 = lds[ptl * 17 + 2 * j];
        uint32_t u1 = lds[ptl * 17 + 2 * j + 1];
        f4v o = { bf_lo(u0), bf_hi(u0), bf_lo(u1), bf_hi(u1) };
        __builtin_nontemporal_store(o, out4 + ob + flat);
    }
}

// ---- Fallback: direct fp32 kernel (correct for any config).
__global__ __launch_bounds__(256) void hashgrid_fallback(
    const float* __restrict__ x, const float* __restrict__ tables,
    float* __restrict__ out, int n_points, Params lp)
{
    int gid = blockIdx.x * blockDim.x + threadIdx.x;
    int n = gid >> 4;
    int l = gid & 15;
    if (n >= n_points) return;
    float x0 = x[(size_t)n * 3 + 0];
    float x1 = x[(size_t)n * 3 + 1];
    float x2 = x[(size_t)n * 3 + 2];
    uint32_t size = lp.size[l];
    uint64_t magic = lp.magic[l];
    float fres = (float)lp.res[l];
    float xr0 = x0 * fres, xr1 = x1 * fres, xr2 = x2 * fres;
    int ci0 = (int)xr0, ci1 = (int)xr1, ci2 = (int)xr2;
    float cf0 = xr0 - (float)ci0, cf1 = xr1 - (float)ci1, cf2 = xr2 - (float)ci2;
    uint32_t h0a = (uint32_t)ci0;               uint32_t h0b = h0a + 1u;
    uint32_t h1a = (uint32_t)ci1 * 2654435761u; uint32_t h1b = h1a + 2654435761u;
    uint32_t h2a = (uint32_t)ci2 * 805459861u;  uint32_t h2b = h2a + 805459861u;
    float w0a = 1.0f - cf0, w1a = 1.0f - cf1, w2a = 1.0f - cf2;
    const float2* t = reinterpret_cast<const float2*>(tables) + (size_t)l * TABLE_SZ;
    float s0 = 0.0f, s1 = 0.0f;
#pragma unroll
    for (int k = 0; k < 8; ++k) {
        uint32_t h = ((k & 1) ? h0b : h0a) ^ ((k & 2) ? h1b : h1a) ^ ((k & 4) ? h2b : h2a);
        uint32_t q = (uint32_t)__umul64hi((uint64_t)h, magic);
        h -= q * size;
        float w = ((k & 1) ? cf0 : w0a) * ((k & 2) ? cf1 : w1a) * ((k & 4) ? cf2 : w2a);
        float2 f = t[h];
        s0 = fmaf(f.x, w, s0);
        s1 = fmaf(f.y, w, s1);
    }
    reinterpret_cast<float2*>(out)[(size_t)n * NLEVELS + l] = make_float2(s0, s1);
}

extern "C" void kernel_launch(void* const* d_in, const int* in_sizes, int n_in,
                              void* d_out, int out_size, void* d_ws, size_t ws_size,
                              hipStream_t stream) {
    const float* x      = (const float*)d_in[0];
    const float* tables = (const float*)d_in[1];
    float* out          = (float*)d_out;
    int n_points = in_sizes[0] / 3;

    // Exact replication of the reference's double-precision level math.
    Params p;
    double b = exp((log(512.0) - log(16.0)) / 15.0);
    for (int i = 0; i < NLEVELS; ++i) {
        double r = floor(16.0 * pow(b, (double)i));
        uint32_t res = (uint32_t)r;
        uint64_t cube = (uint64_t)res * res * res;
        uint32_t size = (cube < (uint64_t)TABLE_SZ) ? (uint32_t)cube : TABLE_SZ;
        p.res[i] = res;
        p.size[i] = size;
        p.magic[i] = ~0ULL / size + 1ULL;
    }
    // Structure assumption for the fast path: levels 0-7 uncapped, 8-15 capped.
    bool shape_ok = true;
    for (int s = 0; s < 8; ++s)
        shape_ok = shape_ok && (p.size[s] < TABLE_SZ) && (p.size[s + 8] == TABLE_SZ);

    const size_t TAB_BYTES = (size_t)NLEVELS * TABLE_SZ * 4;   // 32 MB bf16 tables
    size_t rem = (ws_size > TAB_BYTES) ? ws_size - TAB_BYTES : 0;
    int passN = (int)((rem / (NXCD * sizeof(unsigned long long))) & ~(size_t)255);
    if (passN > n_points) passN = n_points;

    if (!shape_ok || passN < 256 || (n_points & 255) != 0) {
        int total = n_points * NLEVELS;
        hashgrid_fallback<<<(total + 255) / 256, 256, 0, stream>>>(x, tables, out, n_points, p);
        return;
    }

    uint32_t* btab = (uint32_t*)d_ws;
    unsigned long long* ws2 = (unsigned long long*)((char*)d_ws + TAB_BYTES);

    convert_kernel<<<128 * NXCD, 256, 0, stream>>>(tables, btab, p);

    for (int p_lo = 0; p_lo < n_points; p_lo += passN) {
        int cnt = n_points - p_lo;
        if (cnt > passN) cnt = passN;
        int chunks = cnt / 256;
        gather_kernel<<<chunks * NXCD, 256, 0, stream>>>(x, btab, ws2, p_lo, cnt, p);
        transpose_kernel<<<chunks, 256, 0, stream>>>(ws2, (f4v*)out, p_lo, cnt);
    }
}